// Round 6
// baseline (200.976 us; speedup 1.0000x reference)
//
#include <hip/hip_runtime.h>

#define NN 100000
#define DD 384
#define CC 8

typedef unsigned int uint;
typedef _Float16 half2v __attribute__((ext_vector_type(2)));

__device__ __forceinline__ constexpr int TIDX(int i, int j) { return i * (i + 1) / 2 + j; }

__device__ __forceinline__ uint pkh2(float a, float b) {
  return __builtin_bit_cast(uint, __builtin_amdgcn_cvt_pkrtz(a, b));
}

__device__ __forceinline__ float dot2(uint a, uint b, float c) {
#if __has_builtin(__builtin_amdgcn_fdot2)
  return __builtin_amdgcn_fdot2(__builtin_bit_cast(half2v, a),
                                __builtin_bit_cast(half2v, b), c, false);
#else
  half2v ha = __builtin_bit_cast(half2v, a), hb = __builtin_bit_cast(half2v, b);
  return c + (float)ha.x * (float)hb.x + (float)ha.y * (float)hb.y;
#endif
}

// Pack channel-PAIR records as f16x2: pair p covers channels d0=2p, d1=2p+1.
// recpk[p][k] k<36: pack(tri_{d0}[k], tri_{d1}[k]); k=36..43: pack(w_{d0}[k-36], w_{d1}[k-36]).
__global__ __launch_bounds__(64) void vbpca_prep(
    const float* __restrict__ wbar, const float* __restrict__ Sigmaw,
    uint* __restrict__ recpk) {
  int p = blockIdx.x * 64 + threadIdx.x;
  if (p >= DD / 2) return;
  const int d0 = 2 * p, d1 = 2 * p + 1;
  float w0[CC], w1[CC];
#pragma unroll
  for (int i = 0; i < CC; ++i) {
    w0[i] = wbar[d0 * CC + i];
    w1[i] = wbar[d1 * CC + i];
  }
  uint* r = recpk + (size_t)p * 44;
#pragma unroll
  for (int i = 0; i < CC; ++i) {
#pragma unroll
    for (int j = 0; j <= i; ++j) {
      float t0 = Sigmaw[(size_t)d0 * 64 + i * 8 + j] + w0[i] * w0[j];
      float t1 = Sigmaw[(size_t)d1 * 64 + i * 8 + j] + w1[i] * w1[j];
      r[TIDX(i, j)] = pkh2(t0, t1);
    }
  }
#pragma unroll
  for (int j = 0; j < CC; ++j) r[36 + j] = pkh2(w0[j], w1[j]);
}

#define ROWS 64
#define NCHUNK 6

// 256 threads = 4 waves = 4 groups. Group g handles channels [g*96, g*96+96)
// for rows [blk*64, blk*64+64); thread r=tid&63 owns row r. Per chunk (16 ch
// per group): coalesced global load -> f16-pair pack -> LDS transpose -> dot2
// accumulate vs SCALAR-loaded (wave-uniform s_load) records. Tree-reduce, solve.
__global__ __launch_bounds__(256, 6) void vbpca_main(
    const float* __restrict__ Y, const int* __restrict__ O,
    const uint* __restrict__ recpk, const float* __restrict__ mbar,
    const float* __restrict__ vyp, float* __restrict__ out) {
  __shared__ uint smem[6016];  // 24064 B -> 6 blocks/CU
  float* mbar_l = (float*)smem;            // [384] = 1536 B
  uint* tile_l = smem + 384;               // [4][64][18] u32 = 18432 B
  float* part_l = (float*)(smem + 384);    // [2][44][64] f32 = 22528 B (overlay)

  const int tid = threadIdx.x;
  const int g = tid >> 6;
  const int gu = __builtin_amdgcn_readfirstlane(g);
  const int r = tid & 63;
  const int grow = blockIdx.x * ROWS + r;

  for (int i = tid; i < DD; i += 256) mbar_l[i] = mbar[i];

  float4 yv[4];
  int4 ov[4];
#define ISSUE_LOADS(IT)                                                        \
  {                                                                            \
    _Pragma("unroll") for (int q = 0; q < 4; ++q) {                            \
      const int row = tid >> 2, c4 = tid & 3;                                  \
      int rg = blockIdx.x * ROWS + row;                                        \
      rg = rg < NN ? rg : NN - 1;                                              \
      const int ch = q * 96 + (IT)*16 + c4 * 4;                                \
      yv[q] = *reinterpret_cast<const float4*>(Y + (size_t)rg * DD + ch);      \
      ov[q] = *reinterpret_cast<const int4*>(O + (size_t)rg * DD + ch);        \
    }                                                                          \
  }

  ISSUE_LOADS(0);
  __syncthreads();  // mbar ready

  float a[36];
  float pr[CC];
#pragma unroll
  for (int k = 0; k < 36; ++k) a[k] = 0.f;
#pragma unroll
  for (int j = 0; j < CC; ++j) pr[j] = 0.f;

  for (int it = 0; it < NCHUNK; ++it) {
    if (it) __syncthreads();  // previous chunk's tile reads complete

    // Convert + transpose into LDS tile.
#pragma unroll
    for (int q = 0; q < 4; ++q) {
      const int row = tid >> 2, c4 = tid & 3;
      const int ch = q * 96 + it * 16 + c4 * 4;
      const float4 mb = *reinterpret_cast<const float4*>(mbar_l + ch);
      const float o0 = (float)ov[q].x, o1 = (float)ov[q].y;
      const float o2 = (float)ov[q].z, o3 = (float)ov[q].w;
      const float t0 = o0 * (yv[q].x - mb.x), t1 = o1 * (yv[q].y - mb.y);
      const float t2 = o2 * (yv[q].z - mb.z), t3 = o3 * (yv[q].w - mb.w);
      uint* base = tile_l + q * 1152 + row * 18;
      *reinterpret_cast<uint2*>(base + c4 * 2) = make_uint2(pkh2(o0, o1), pkh2(o2, o3));
      *reinterpret_cast<uint2*>(base + 8 + c4 * 2) = make_uint2(pkh2(t0, t1), pkh2(t2, t3));
    }
    if (it + 1 < NCHUNK) ISSUE_LOADS(it + 1);  // in flight under compute
    __syncthreads();

    // Load this thread's 8 channel-pairs from LDS tile.
    uint ofv[8], tvv[8];
    const uint* trow = tile_l + gu * 1152 + r * 18;
    *reinterpret_cast<uint2*>(&ofv[0]) = *reinterpret_cast<const uint2*>(trow + 0);
    *reinterpret_cast<uint2*>(&ofv[2]) = *reinterpret_cast<const uint2*>(trow + 2);
    *reinterpret_cast<uint2*>(&ofv[4]) = *reinterpret_cast<const uint2*>(trow + 4);
    *reinterpret_cast<uint2*>(&ofv[6]) = *reinterpret_cast<const uint2*>(trow + 6);
    *reinterpret_cast<uint2*>(&tvv[0]) = *reinterpret_cast<const uint2*>(trow + 8);
    *reinterpret_cast<uint2*>(&tvv[2]) = *reinterpret_cast<const uint2*>(trow + 10);
    *reinterpret_cast<uint2*>(&tvv[4]) = *reinterpret_cast<const uint2*>(trow + 12);
    *reinterpret_cast<uint2*>(&tvv[6]) = *reinterpret_cast<const uint2*>(trow + 14);

#pragma unroll
    for (int p = 0; p < 8; ++p) {
      // Wave-uniform record address -> scalar s_load stream (SMEM pipe).
      const uint4* rp =
          reinterpret_cast<const uint4*>(recpk) + (size_t)(gu * 48 + it * 8 + p) * 11;
      const uint A = ofv[p], T = tvv[p];
      uint4 R;
      R = rp[0];
      a[0] = dot2(A, R.x, a[0]); a[1] = dot2(A, R.y, a[1]);
      a[2] = dot2(A, R.z, a[2]); a[3] = dot2(A, R.w, a[3]);
      R = rp[1];
      a[4] = dot2(A, R.x, a[4]); a[5] = dot2(A, R.y, a[5]);
      a[6] = dot2(A, R.z, a[6]); a[7] = dot2(A, R.w, a[7]);
      R = rp[2];
      a[8] = dot2(A, R.x, a[8]); a[9] = dot2(A, R.y, a[9]);
      a[10] = dot2(A, R.z, a[10]); a[11] = dot2(A, R.w, a[11]);
      R = rp[3];
      a[12] = dot2(A, R.x, a[12]); a[13] = dot2(A, R.y, a[13]);
      a[14] = dot2(A, R.z, a[14]); a[15] = dot2(A, R.w, a[15]);
      R = rp[4];
      a[16] = dot2(A, R.x, a[16]); a[17] = dot2(A, R.y, a[17]);
      a[18] = dot2(A, R.z, a[18]); a[19] = dot2(A, R.w, a[19]);
      R = rp[5];
      a[20] = dot2(A, R.x, a[20]); a[21] = dot2(A, R.y, a[21]);
      a[22] = dot2(A, R.z, a[22]); a[23] = dot2(A, R.w, a[23]);
      R = rp[6];
      a[24] = dot2(A, R.x, a[24]); a[25] = dot2(A, R.y, a[25]);
      a[26] = dot2(A, R.z, a[26]); a[27] = dot2(A, R.w, a[27]);
      R = rp[7];
      a[28] = dot2(A, R.x, a[28]); a[29] = dot2(A, R.y, a[29]);
      a[30] = dot2(A, R.z, a[30]); a[31] = dot2(A, R.w, a[31]);
      R = rp[8];
      a[32] = dot2(A, R.x, a[32]); a[33] = dot2(A, R.y, a[33]);
      a[34] = dot2(A, R.z, a[34]); a[35] = dot2(A, R.w, a[35]);
      R = rp[9];
      pr[0] = dot2(T, R.x, pr[0]); pr[1] = dot2(T, R.y, pr[1]);
      pr[2] = dot2(T, R.z, pr[2]); pr[3] = dot2(T, R.w, pr[3]);
      R = rp[10];
      pr[4] = dot2(T, R.x, pr[4]); pr[5] = dot2(T, R.y, pr[5]);
      pr[6] = dot2(T, R.z, pr[6]); pr[7] = dot2(T, R.w, pr[7]);
    }
  }

  // ---- two-phase tree reduction over 4 groups (part overlays tile) ----
  __syncthreads();  // all tile reads done before overwrite
  if (g == 1 || g == 3) {
    float* dst = part_l + (g >> 1) * 2816;  // g1 -> part[0], g3 -> part[1]
#pragma unroll
    for (int k = 0; k < 36; ++k) dst[k * 64 + r] = a[k];
#pragma unroll
    for (int j = 0; j < CC; ++j) dst[(36 + j) * 64 + r] = pr[j];
  }
  __syncthreads();
  if (g == 0 || g == 2) {
    const float* src = part_l + (g >> 1) * 2816;
#pragma unroll
    for (int k = 0; k < 36; ++k) a[k] += src[k * 64 + r];
#pragma unroll
    for (int j = 0; j < CC; ++j) pr[j] += src[(36 + j) * 64 + r];
  }
  __syncthreads();
  if (g == 2) {
#pragma unroll
    for (int k = 0; k < 36; ++k) part_l[k * 64 + r] = a[k];
#pragma unroll
    for (int j = 0; j < CC; ++j) part_l[(36 + j) * 64 + r] = pr[j];
  }
  __syncthreads();
  if (g != 0) return;
#pragma unroll
  for (int k = 0; k < 36; ++k) a[k] += part_l[k * 64 + r];
#pragma unroll
  for (int j = 0; j < CC; ++j) pr[j] += part_l[(36 + j) * 64 + r];

  const float vy = *vyp;

  // ---- Cholesky solve: M = vy*I + A ----
  float L[36];
#pragma unroll
  for (int j = 0; j < CC; ++j) {
    float s = a[TIDX(j, j)] + vy;
#pragma unroll
    for (int k = 0; k < CC; ++k) {
      if (k < j) s -= L[TIDX(j, k)] * L[TIDX(j, k)];
    }
    const float dj = sqrtf(s);
    L[TIDX(j, j)] = dj;
    const float invdj = 1.0f / dj;
#pragma unroll
    for (int i = j + 1; i < CC; ++i) {
      float tt = a[TIDX(i, j)];
#pragma unroll
      for (int k = 0; k < CC; ++k) {
        if (k < j) tt -= L[TIDX(i, k)] * L[TIDX(j, k)];
      }
      L[TIDX(i, j)] = tt * invdj;
    }
  }

  float invd[CC];
#pragma unroll
  for (int i = 0; i < CC; ++i) invd[i] = 1.0f / L[TIDX(i, i)];
  float Li[36];
#pragma unroll
  for (int j = 0; j < CC; ++j) {
    Li[TIDX(j, j)] = invd[j];
#pragma unroll
    for (int i = j + 1; i < CC; ++i) {
      float s = 0.f;
#pragma unroll
      for (int k = 0; k < CC; ++k) {
        if (k >= j && k < i) s += L[TIDX(i, k)] * Li[TIDX(k, j)];
      }
      Li[TIDX(i, j)] = -s * invd[i];
    }
  }

  float sig[36];
#pragma unroll
  for (int i = 0; i < CC; ++i) {
#pragma unroll
    for (int j = 0; j <= i; ++j) {
      float s = 0.f;
#pragma unroll
      for (int k = 0; k < CC; ++k) {
        if (k >= i) s += Li[TIDX(k, i)] * Li[TIDX(k, j)];
      }
      sig[TIDX(i, j)] = vy * s;
    }
  }

  float uvec[CC];
#pragma unroll
  for (int i = 0; i < CC; ++i) {
    float s = 0.f;
#pragma unroll
    for (int j = 0; j < CC; ++j) {
      if (j <= i) s += Li[TIDX(i, j)] * pr[j];
    }
    uvec[i] = s;
  }
  float xb[CC];
#pragma unroll
  for (int l = 0; l < CC; ++l) {
    float s = 0.f;
#pragma unroll
    for (int i = 0; i < CC; ++i) {
      if (i >= l) s += Li[TIDX(i, l)] * uvec[i];
    }
    xb[l] = s;
  }

  if (grow >= NN) return;

  float4* __restrict__ xo = reinterpret_cast<float4*>(out + (size_t)grow * CC);
  xo[0] = make_float4(xb[0], xb[1], xb[2], xb[3]);
  xo[1] = make_float4(xb[4], xb[5], xb[6], xb[7]);

  float4* __restrict__ so4 =
      reinterpret_cast<float4*>(out + (size_t)NN * CC + (size_t)grow * 64);
#pragma unroll
  for (int i = 0; i < CC; ++i) {
    float rowv[CC];
#pragma unroll
    for (int j = 0; j < CC; ++j) {
      rowv[j] = (j <= i) ? sig[TIDX(i, j)] : sig[TIDX(j, i)];
    }
    so4[i * 2 + 0] = make_float4(rowv[0], rowv[1], rowv[2], rowv[3]);
    so4[i * 2 + 1] = make_float4(rowv[4], rowv[5], rowv[6], rowv[7]);
  }
}

extern "C" void kernel_launch(void* const* d_in, const int* in_sizes, int n_in,
                              void* d_out, int out_size, void* d_ws, size_t ws_size,
                              hipStream_t stream) {
  const float* Y = (const float*)d_in[0];
  const int* O = (const int*)d_in[1];
  const float* mbar = (const float*)d_in[2];
  const float* wbar = (const float*)d_in[3];
  const float* Sigmaw = (const float*)d_in[4];
  const float* vyp = (const float*)d_in[5];
  float* out = (float*)d_out;
  uint* recpk = (uint*)d_ws;  // 192*44*4 = 33792 bytes

  vbpca_prep<<<3, 64, 0, stream>>>(wbar, Sigmaw, recpk);
  vbpca_main<<<(NN + ROWS - 1) / ROWS, 256, 0, stream>>>(Y, O, recpk, mbar, vyp, out);
}

// Round 7
// 126.279 us; speedup vs baseline: 1.5915x; 1.5915x over previous
//
#include <hip/hip_runtime.h>

#define NN 100000
#define DD 384
#define CC 8

typedef unsigned int uint;
typedef _Float16 half2v __attribute__((ext_vector_type(2)));

__device__ __forceinline__ constexpr int TIDX(int i, int j) { return i * (i + 1) / 2 + j; }

__device__ __forceinline__ uint pkh2(float a, float b) {
  return __builtin_bit_cast(uint, __builtin_amdgcn_cvt_pkrtz(a, b));
}

__device__ __forceinline__ float dot2(uint a, uint b, float c) {
#if __has_builtin(__builtin_amdgcn_fdot2)
  return __builtin_amdgcn_fdot2(__builtin_bit_cast(half2v, a),
                                __builtin_bit_cast(half2v, b), c, false);
#else
  half2v ha = __builtin_bit_cast(half2v, a), hb = __builtin_bit_cast(half2v, b);
  return c + (float)ha.x * (float)hb.x + (float)ha.y * (float)hb.y;
#endif
}

// Pack channel-PAIR records as f16x2: pair p covers channels d0=2p, d1=2p+1.
// recpk[p][k] k<36: pack(tri_{d0}[k], tri_{d1}[k]); k=36..43: pack(w_{d0}[k-36], w_{d1}[k-36]).
__global__ __launch_bounds__(64) void vbpca_prep(
    const float* __restrict__ wbar, const float* __restrict__ Sigmaw,
    uint* __restrict__ recpk) {
  int p = blockIdx.x * 64 + threadIdx.x;
  if (p >= DD / 2) return;
  const int d0 = 2 * p, d1 = 2 * p + 1;
  float w0[CC], w1[CC];
#pragma unroll
  for (int i = 0; i < CC; ++i) {
    w0[i] = wbar[d0 * CC + i];
    w1[i] = wbar[d1 * CC + i];
  }
  uint* r = recpk + (size_t)p * 44;
#pragma unroll
  for (int i = 0; i < CC; ++i) {
#pragma unroll
    for (int j = 0; j <= i; ++j) {
      float t0 = Sigmaw[(size_t)d0 * 64 + i * 8 + j] + w0[i] * w0[j];
      float t1 = Sigmaw[(size_t)d1 * 64 + i * 8 + j] + w1[i] * w1[j];
      r[TIDX(i, j)] = pkh2(t0, t1);
    }
  }
#pragma unroll
  for (int j = 0; j < CC; ++j) r[36 + j] = pkh2(w0[j], w1[j]);
}

#define ROWS 64
#define NCHUNK 6

// 256 threads = 4 waves = 4 groups. Group g handles channels [g*96, g*96+96)
// for rows [blk*64, blk*64+64); thread r=tid&63 owns row r. Per chunk (16 ch
// per group): coalesced global load -> f16-pair pack -> LDS transpose -> dot2
// accumulate vs SCALAR-loaded (wave-uniform s_load) records, tile packs read
// just-in-time (2 x ds_read_b32 per pair) to keep VGPR under the (256,5) cap.
__global__ __launch_bounds__(256, 5) void vbpca_main(
    const float* __restrict__ Y, const int* __restrict__ O,
    const uint* __restrict__ recpk, const float* __restrict__ mbar,
    const float* __restrict__ vyp, float* __restrict__ out) {
  __shared__ uint smem[6016];  // 24064 B
  float* mbar_l = (float*)smem;            // [384] = 1536 B
  uint* tile_l = smem + 384;               // [4][64][18] u32 = 18432 B
  float* part_l = (float*)(smem + 384);    // [2][44][64] f32 = 22528 B (overlay)

  const int tid = threadIdx.x;
  const int g = tid >> 6;
  const int gu = __builtin_amdgcn_readfirstlane(g);
  const int r = tid & 63;
  const int grow = blockIdx.x * ROWS + r;

  for (int i = tid; i < DD; i += 256) mbar_l[i] = mbar[i];

  float4 yv[4];
  int4 ov[4];
#define ISSUE_LOADS(IT)                                                        \
  {                                                                            \
    _Pragma("unroll") for (int q = 0; q < 4; ++q) {                            \
      const int row = tid >> 2, c4 = tid & 3;                                  \
      int rg = blockIdx.x * ROWS + row;                                        \
      rg = rg < NN ? rg : NN - 1;                                              \
      const int ch = q * 96 + (IT)*16 + c4 * 4;                                \
      yv[q] = *reinterpret_cast<const float4*>(Y + (size_t)rg * DD + ch);      \
      ov[q] = *reinterpret_cast<const int4*>(O + (size_t)rg * DD + ch);        \
    }                                                                          \
  }

  ISSUE_LOADS(0);
  __syncthreads();  // mbar ready

  float a[36];
  float pr[CC];
#pragma unroll
  for (int k = 0; k < 36; ++k) a[k] = 0.f;
#pragma unroll
  for (int j = 0; j < CC; ++j) pr[j] = 0.f;

  for (int it = 0; it < NCHUNK; ++it) {
    if (it) __syncthreads();  // previous chunk's tile reads complete

    // Convert + transpose into LDS tile.
#pragma unroll
    for (int q = 0; q < 4; ++q) {
      const int row = tid >> 2, c4 = tid & 3;
      const int ch = q * 96 + it * 16 + c4 * 4;
      const float4 mb = *reinterpret_cast<const float4*>(mbar_l + ch);
      const float o0 = (float)ov[q].x, o1 = (float)ov[q].y;
      const float o2 = (float)ov[q].z, o3 = (float)ov[q].w;
      const float t0 = o0 * (yv[q].x - mb.x), t1 = o1 * (yv[q].y - mb.y);
      const float t2 = o2 * (yv[q].z - mb.z), t3 = o3 * (yv[q].w - mb.w);
      uint* base = tile_l + q * 1152 + row * 18;
      *reinterpret_cast<uint2*>(base + c4 * 2) = make_uint2(pkh2(o0, o1), pkh2(o2, o3));
      *reinterpret_cast<uint2*>(base + 8 + c4 * 2) = make_uint2(pkh2(t0, t1), pkh2(t2, t3));
    }
    if (it + 1 < NCHUNK) ISSUE_LOADS(it + 1);  // in flight under compute
    __syncthreads();

    const uint* trow = tile_l + gu * 1152 + r * 18;
#pragma unroll
    for (int p = 0; p < 8; ++p) {
      // Wave-uniform record address -> scalar s_load stream (SMEM pipe).
      const uint4* rp =
          reinterpret_cast<const uint4*>(recpk) + (size_t)(gu * 48 + it * 8 + p) * 11;
      const uint A = trow[p];      // JIT ds_read_b32
      const uint T = trow[8 + p];  // JIT ds_read_b32
      uint4 R;
      R = rp[0];
      a[0] = dot2(A, R.x, a[0]); a[1] = dot2(A, R.y, a[1]);
      a[2] = dot2(A, R.z, a[2]); a[3] = dot2(A, R.w, a[3]);
      R = rp[1];
      a[4] = dot2(A, R.x, a[4]); a[5] = dot2(A, R.y, a[5]);
      a[6] = dot2(A, R.z, a[6]); a[7] = dot2(A, R.w, a[7]);
      R = rp[2];
      a[8] = dot2(A, R.x, a[8]); a[9] = dot2(A, R.y, a[9]);
      a[10] = dot2(A, R.z, a[10]); a[11] = dot2(A, R.w, a[11]);
      R = rp[3];
      a[12] = dot2(A, R.x, a[12]); a[13] = dot2(A, R.y, a[13]);
      a[14] = dot2(A, R.z, a[14]); a[15] = dot2(A, R.w, a[15]);
      R = rp[4];
      a[16] = dot2(A, R.x, a[16]); a[17] = dot2(A, R.y, a[17]);
      a[18] = dot2(A, R.z, a[18]); a[19] = dot2(A, R.w, a[19]);
      R = rp[5];
      a[20] = dot2(A, R.x, a[20]); a[21] = dot2(A, R.y, a[21]);
      a[22] = dot2(A, R.z, a[22]); a[23] = dot2(A, R.w, a[23]);
      R = rp[6];
      a[24] = dot2(A, R.x, a[24]); a[25] = dot2(A, R.y, a[25]);
      a[26] = dot2(A, R.z, a[26]); a[27] = dot2(A, R.w, a[27]);
      R = rp[7];
      a[28] = dot2(A, R.x, a[28]); a[29] = dot2(A, R.y, a[29]);
      a[30] = dot2(A, R.z, a[30]); a[31] = dot2(A, R.w, a[31]);
      R = rp[8];
      a[32] = dot2(A, R.x, a[32]); a[33] = dot2(A, R.y, a[33]);
      a[34] = dot2(A, R.z, a[34]); a[35] = dot2(A, R.w, a[35]);
      R = rp[9];
      pr[0] = dot2(T, R.x, pr[0]); pr[1] = dot2(T, R.y, pr[1]);
      pr[2] = dot2(T, R.z, pr[2]); pr[3] = dot2(T, R.w, pr[3]);
      R = rp[10];
      pr[4] = dot2(T, R.x, pr[4]); pr[5] = dot2(T, R.y, pr[5]);
      pr[6] = dot2(T, R.z, pr[6]); pr[7] = dot2(T, R.w, pr[7]);
    }
  }

  // ---- two-phase tree reduction over 4 groups (part overlays tile) ----
  __syncthreads();  // all tile reads done before overwrite
  if (g == 1 || g == 3) {
    float* dst = part_l + (g >> 1) * 2816;  // g1 -> part[0], g3 -> part[1]
#pragma unroll
    for (int k = 0; k < 36; ++k) dst[k * 64 + r] = a[k];
#pragma unroll
    for (int j = 0; j < CC; ++j) dst[(36 + j) * 64 + r] = pr[j];
  }
  __syncthreads();
  if (g == 0 || g == 2) {
    const float* src = part_l + (g >> 1) * 2816;
#pragma unroll
    for (int k = 0; k < 36; ++k) a[k] += src[k * 64 + r];
#pragma unroll
    for (int j = 0; j < CC; ++j) pr[j] += src[(36 + j) * 64 + r];
  }
  __syncthreads();
  if (g == 2) {
#pragma unroll
    for (int k = 0; k < 36; ++k) part_l[k * 64 + r] = a[k];
#pragma unroll
    for (int j = 0; j < CC; ++j) part_l[(36 + j) * 64 + r] = pr[j];
  }
  __syncthreads();
  if (g != 0) return;
#pragma unroll
  for (int k = 0; k < 36; ++k) a[k] += part_l[k * 64 + r];
#pragma unroll
  for (int j = 0; j < CC; ++j) pr[j] += part_l[(36 + j) * 64 + r];

  const float vy = *vyp;

  // ---- Cholesky solve: M = vy*I + A ----
  float L[36];
#pragma unroll
  for (int j = 0; j < CC; ++j) {
    float s = a[TIDX(j, j)] + vy;
#pragma unroll
    for (int k = 0; k < CC; ++k) {
      if (k < j) s -= L[TIDX(j, k)] * L[TIDX(j, k)];
    }
    const float dj = sqrtf(s);
    L[TIDX(j, j)] = dj;
    const float invdj = 1.0f / dj;
#pragma unroll
    for (int i = j + 1; i < CC; ++i) {
      float tt = a[TIDX(i, j)];
#pragma unroll
      for (int k = 0; k < CC; ++k) {
        if (k < j) tt -= L[TIDX(i, k)] * L[TIDX(j, k)];
      }
      L[TIDX(i, j)] = tt * invdj;
    }
  }

  float invd[CC];
#pragma unroll
  for (int i = 0; i < CC; ++i) invd[i] = 1.0f / L[TIDX(i, i)];
  float Li[36];
#pragma unroll
  for (int j = 0; j < CC; ++j) {
    Li[TIDX(j, j)] = invd[j];
#pragma unroll
    for (int i = j + 1; i < CC; ++i) {
      float s = 0.f;
#pragma unroll
      for (int k = 0; k < CC; ++k) {
        if (k >= j && k < i) s += L[TIDX(i, k)] * Li[TIDX(k, j)];
      }
      Li[TIDX(i, j)] = -s * invd[i];
    }
  }

  float sig[36];
#pragma unroll
  for (int i = 0; i < CC; ++i) {
#pragma unroll
    for (int j = 0; j <= i; ++j) {
      float s = 0.f;
#pragma unroll
      for (int k = 0; k < CC; ++k) {
        if (k >= i) s += Li[TIDX(k, i)] * Li[TIDX(k, j)];
      }
      sig[TIDX(i, j)] = vy * s;
    }
  }

  float uvec[CC];
#pragma unroll
  for (int i = 0; i < CC; ++i) {
    float s = 0.f;
#pragma unroll
    for (int j = 0; j < CC; ++j) {
      if (j <= i) s += Li[TIDX(i, j)] * pr[j];
    }
    uvec[i] = s;
  }
  float xb[CC];
#pragma unroll
  for (int l = 0; l < CC; ++l) {
    float s = 0.f;
#pragma unroll
    for (int i = 0; i < CC; ++i) {
      if (i >= l) s += Li[TIDX(i, l)] * uvec[i];
    }
    xb[l] = s;
  }

  if (grow >= NN) return;

  float4* __restrict__ xo = reinterpret_cast<float4*>(out + (size_t)grow * CC);
  xo[0] = make_float4(xb[0], xb[1], xb[2], xb[3]);
  xo[1] = make_float4(xb[4], xb[5], xb[6], xb[7]);

  float4* __restrict__ so4 =
      reinterpret_cast<float4*>(out + (size_t)NN * CC + (size_t)grow * 64);
#pragma unroll
  for (int i = 0; i < CC; ++i) {
    float rowv[CC];
#pragma unroll
    for (int j = 0; j < CC; ++j) {
      rowv[j] = (j <= i) ? sig[TIDX(i, j)] : sig[TIDX(j, i)];
    }
    so4[i * 2 + 0] = make_float4(rowv[0], rowv[1], rowv[2], rowv[3]);
    so4[i * 2 + 1] = make_float4(rowv[4], rowv[5], rowv[6], rowv[7]);
  }
}

extern "C" void kernel_launch(void* const* d_in, const int* in_sizes, int n_in,
                              void* d_out, int out_size, void* d_ws, size_t ws_size,
                              hipStream_t stream) {
  const float* Y = (const float*)d_in[0];
  const int* O = (const int*)d_in[1];
  const float* mbar = (const float*)d_in[2];
  const float* wbar = (const float*)d_in[3];
  const float* Sigmaw = (const float*)d_in[4];
  const float* vyp = (const float*)d_in[5];
  float* out = (float*)d_out;
  uint* recpk = (uint*)d_ws;  // 192*44*4 = 33792 bytes

  vbpca_prep<<<3, 64, 0, stream>>>(wbar, Sigmaw, recpk);
  vbpca_main<<<(NN + ROWS - 1) / ROWS, 256, 0, stream>>>(Y, O, recpk, mbar, vyp, out);
}

// Round 8
// 92.520 us; speedup vs baseline: 2.1723x; 1.3649x over previous
//
#include <hip/hip_runtime.h>

#define NN 100000
#define DD 384
#define CC 8
#define ROWS 64

typedef unsigned int uint;
typedef _Float16 half8 __attribute__((ext_vector_type(8)));
typedef float floatx4 __attribute__((ext_vector_type(4)));

__device__ __forceinline__ constexpr int TIDX(int i, int j) { return i * (i + 1) / 2 + j; }

__device__ __forceinline__ uint pkh2(float a, float b) {
  return __builtin_bit_cast(uint, __builtin_amdgcn_cvt_pkrtz(a, b));
}

// B-fragment pre-pack. B[d][col]: col 0..35 = lower-tri of Sigmaw[d]+w w^T,
// col 36..43 = wbar[d][col-36], col 44..47 = 0.
// Fragment layout for mfma_f32_16x16x32_f16 B-operand: lane holds 8 f16 at
// col = ct*16 + (lane&15), k(j) = kt*32 + (lane>>4)*8 + j  (j = in-lane order).
// bfrag[(kt*3+ct)*64 + lane] = uint4 (8 f16).
__global__ __launch_bounds__(64) void vbpca_prep(
    const float* __restrict__ wbar, const float* __restrict__ Sigmaw,
    uint4* __restrict__ bfrag) {
  const int l = threadIdx.x;
  const int kt = blockIdx.x;  // 0..11
  const int kgrp = l >> 4;
#pragma unroll
  for (int ct = 0; ct < 3; ++ct) {
    const int col = ct * 16 + (l & 15);
    int ii = 0;
#pragma unroll
    for (int t = 0; t < 7; ++t) {  // decode row index for col<36
      if ((ii + 1) * (ii + 2) / 2 <= col && ii < 7) ++ii;
    }
    const int jj = col - ii * (ii + 1) / 2;
    float v[8];
#pragma unroll
    for (int j = 0; j < 8; ++j) {
      const int d = kt * 32 + kgrp * 8 + j;
      float val;
      if (col < 36) {
        val = Sigmaw[(size_t)d * 64 + ii * 8 + jj] + wbar[d * 8 + ii] * wbar[d * 8 + jj];
      } else if (col < 44) {
        val = wbar[d * 8 + (col - 36)];
      } else {
        val = 0.f;
      }
      v[j] = val;
    }
    uint4 u;
    u.x = pkh2(v[0], v[1]); u.y = pkh2(v[2], v[3]);
    u.z = pkh2(v[4], v[5]); u.w = pkh2(v[6], v[7]);
    bfrag[(kt * 3 + ct) * 64 + l] = u;
  }
}

// 256 threads = 4 waves; block owns 64 rows -> 128 interleaved A-rows
// (A-row 2r = O-mask of row r, A-row 2r+1 = O*(Y-mbar)). Per k-tile (32 ch):
// coalesced Y/O load -> f16 pack -> LDS tile [128][32] -> each wave MFMAs its
// 2 row-tiles x 3 col-tiles. Epilogue: scatter C via LDS (49-pad), Cholesky.
__global__ __launch_bounds__(256, 5) void vbpca_main(
    const float* __restrict__ Y, const int* __restrict__ O,
    const uint4* __restrict__ bfrag, const float* __restrict__ mbar,
    const float* __restrict__ vyp, float* __restrict__ out) {
  __shared__ float smemf[6656];  // 26624 B
  float* mbar_l = smemf;                    // [384]
  uint* tile_l = (uint*)(smemf + 384);      // half[128 Arows][32 ch] = 8192 B
  float* scat_l = smemf + 384;              // float[128][49] overlay = 25088 B

  const int tid = threadIdx.x;
  const int l = tid & 63;
  const int w = tid >> 6;

  for (int i = tid; i < DD; i += 256) mbar_l[i] = mbar[i];

  const int lrow0 = tid >> 3;  // 0..31
  const int c4 = tid & 7;      // 0..7
  int rg0 = blockIdx.x * ROWS + lrow0;
  if (rg0 >= NN) rg0 = NN - 1;
  int rg1 = blockIdx.x * ROWS + lrow0 + 32;
  if (rg1 >= NN) rg1 = NN - 1;

  float4 y0, y1;
  int4 o0, o1;
#define ISSUE(KT)                                                          \
  {                                                                        \
    const size_t off0 = (size_t)rg0 * DD + (KT) * 32 + c4 * 4;             \
    const size_t off1 = (size_t)rg1 * DD + (KT) * 32 + c4 * 4;             \
    y0 = *reinterpret_cast<const float4*>(Y + off0);                       \
    o0 = *reinterpret_cast<const int4*>(O + off0);                         \
    y1 = *reinterpret_cast<const float4*>(Y + off1);                       \
    o1 = *reinterpret_cast<const int4*>(O + off1);                         \
  }

  ISSUE(0);

  floatx4 acc[2][3];
#pragma unroll
  for (int i = 0; i < 2; ++i)
#pragma unroll
    for (int j = 0; j < 3; ++j) acc[i][j] = (floatx4){0.f, 0.f, 0.f, 0.f};

  __syncthreads();  // mbar ready

  for (int kt = 0; kt < 12; ++kt) {
    // ---- pack phase: write (o, t) f16 rows into tile ----
    {
      const float4 mb = *reinterpret_cast<const float4*>(mbar_l + kt * 32 + c4 * 4);
      {
        const float f0 = (float)o0.x, f1 = (float)o0.y, f2 = (float)o0.z, f3 = (float)o0.w;
        uint* b0 = tile_l + (2 * lrow0) * 16 + c4 * 2;
        b0[0] = pkh2(f0, f1);
        b0[1] = pkh2(f2, f3);
        uint* b1 = tile_l + (2 * lrow0 + 1) * 16 + c4 * 2;
        b1[0] = pkh2(f0 * (y0.x - mb.x), f1 * (y0.y - mb.y));
        b1[1] = pkh2(f2 * (y0.z - mb.z), f3 * (y0.w - mb.w));
      }
      {
        const float f0 = (float)o1.x, f1 = (float)o1.y, f2 = (float)o1.z, f3 = (float)o1.w;
        uint* b0 = tile_l + (2 * (lrow0 + 32)) * 16 + c4 * 2;
        b0[0] = pkh2(f0, f1);
        b0[1] = pkh2(f2, f3);
        uint* b1 = tile_l + (2 * (lrow0 + 32) + 1) * 16 + c4 * 2;
        b1[0] = pkh2(f0 * (y1.x - mb.x), f1 * (y1.y - mb.y));
        b1[1] = pkh2(f2 * (y1.z - mb.z), f3 * (y1.w - mb.w));
      }
    }
    if (kt < 11) ISSUE(kt + 1);  // next k-tile loads in flight under MFMA phase
    __syncthreads();

    // ---- MFMA phase ----
    {
      const int rt0 = 2 * w, rt1 = 2 * w + 1;
      const half8 a0 = *reinterpret_cast<const half8*>(
          tile_l + (rt0 * 16 + (l & 15)) * 16 + (l >> 4) * 4);
      const half8 a1 = *reinterpret_cast<const half8*>(
          tile_l + (rt1 * 16 + (l & 15)) * 16 + (l >> 4) * 4);
      const uint4 B0 = bfrag[(kt * 3 + 0) * 64 + l];
      const uint4 B1 = bfrag[(kt * 3 + 1) * 64 + l];
      const uint4 B2 = bfrag[(kt * 3 + 2) * 64 + l];
      const half8 b0 = __builtin_bit_cast(half8, B0);
      const half8 b1 = __builtin_bit_cast(half8, B1);
      const half8 b2 = __builtin_bit_cast(half8, B2);
      acc[0][0] = __builtin_amdgcn_mfma_f32_16x16x32_f16(a0, b0, acc[0][0], 0, 0, 0);
      acc[0][1] = __builtin_amdgcn_mfma_f32_16x16x32_f16(a0, b1, acc[0][1], 0, 0, 0);
      acc[0][2] = __builtin_amdgcn_mfma_f32_16x16x32_f16(a0, b2, acc[0][2], 0, 0, 0);
      acc[1][0] = __builtin_amdgcn_mfma_f32_16x16x32_f16(a1, b0, acc[1][0], 0, 0, 0);
      acc[1][1] = __builtin_amdgcn_mfma_f32_16x16x32_f16(a1, b1, acc[1][1], 0, 0, 0);
      acc[1][2] = __builtin_amdgcn_mfma_f32_16x16x32_f16(a1, b2, acc[1][2], 0, 0, 0);
    }
    __syncthreads();
  }

  // ---- epilogue: scatter C into LDS (C/D layout: col=l&15, row=(l>>4)*4+reg) ----
#pragma unroll
  for (int rtl = 0; rtl < 2; ++rtl) {
    const int rt = 2 * w + rtl;
#pragma unroll
    for (int ct = 0; ct < 3; ++ct) {
#pragma unroll
      for (int reg = 0; reg < 4; ++reg) {
        scat_l[(rt * 16 + (l >> 4) * 4 + reg) * 49 + ct * 16 + (l & 15)] =
            acc[rtl][ct][reg];
      }
    }
  }
  __syncthreads();
  if (tid >= 64) return;

  const int row = tid;
  const int grow = blockIdx.x * ROWS + row;

  float a[36], pr[CC];
#pragma unroll
  for (int k = 0; k < 36; ++k) a[k] = scat_l[(2 * row) * 49 + k];
#pragma unroll
  for (int j = 0; j < CC; ++j) pr[j] = scat_l[(2 * row + 1) * 49 + 36 + j];

  const float vy = *vyp;

  // ---- Cholesky solve: M = vy*I + A ----
  float L[36];
#pragma unroll
  for (int j = 0; j < CC; ++j) {
    float s = a[TIDX(j, j)] + vy;
#pragma unroll
    for (int k = 0; k < CC; ++k) {
      if (k < j) s -= L[TIDX(j, k)] * L[TIDX(j, k)];
    }
    const float dj = sqrtf(s);
    L[TIDX(j, j)] = dj;
    const float invdj = 1.0f / dj;
#pragma unroll
    for (int i = j + 1; i < CC; ++i) {
      float tt = a[TIDX(i, j)];
#pragma unroll
      for (int k = 0; k < CC; ++k) {
        if (k < j) tt -= L[TIDX(i, k)] * L[TIDX(j, k)];
      }
      L[TIDX(i, j)] = tt * invdj;
    }
  }

  float invd[CC];
#pragma unroll
  for (int i = 0; i < CC; ++i) invd[i] = 1.0f / L[TIDX(i, i)];
  float Li[36];
#pragma unroll
  for (int j = 0; j < CC; ++j) {
    Li[TIDX(j, j)] = invd[j];
#pragma unroll
    for (int i = j + 1; i < CC; ++i) {
      float s = 0.f;
#pragma unroll
      for (int k = 0; k < CC; ++k) {
        if (k >= j && k < i) s += L[TIDX(i, k)] * Li[TIDX(k, j)];
      }
      Li[TIDX(i, j)] = -s * invd[i];
    }
  }

  float sig[36];
#pragma unroll
  for (int i = 0; i < CC; ++i) {
#pragma unroll
    for (int j = 0; j <= i; ++j) {
      float s = 0.f;
#pragma unroll
      for (int k = 0; k < CC; ++k) {
        if (k >= i) s += Li[TIDX(k, i)] * Li[TIDX(k, j)];
      }
      sig[TIDX(i, j)] = vy * s;
    }
  }

  float uvec[CC];
#pragma unroll
  for (int i = 0; i < CC; ++i) {
    float s = 0.f;
#pragma unroll
    for (int j = 0; j < CC; ++j) {
      if (j <= i) s += Li[TIDX(i, j)] * pr[j];
    }
    uvec[i] = s;
  }
  float xb[CC];
#pragma unroll
  for (int ll = 0; ll < CC; ++ll) {
    float s = 0.f;
#pragma unroll
    for (int i = 0; i < CC; ++i) {
      if (i >= ll) s += Li[TIDX(i, ll)] * uvec[i];
    }
    xb[ll] = s;
  }

  if (grow >= NN) return;

  float4* __restrict__ xo = reinterpret_cast<float4*>(out + (size_t)grow * CC);
  xo[0] = make_float4(xb[0], xb[1], xb[2], xb[3]);
  xo[1] = make_float4(xb[4], xb[5], xb[6], xb[7]);

  float4* __restrict__ so4 =
      reinterpret_cast<float4*>(out + (size_t)NN * CC + (size_t)grow * 64);
#pragma unroll
  for (int i = 0; i < CC; ++i) {
    float rowv[CC];
#pragma unroll
    for (int j = 0; j < CC; ++j) {
      rowv[j] = (j <= i) ? sig[TIDX(i, j)] : sig[TIDX(j, i)];
    }
    so4[i * 2 + 0] = make_float4(rowv[0], rowv[1], rowv[2], rowv[3]);
    so4[i * 2 + 1] = make_float4(rowv[4], rowv[5], rowv[6], rowv[7]);
  }
}

extern "C" void kernel_launch(void* const* d_in, const int* in_sizes, int n_in,
                              void* d_out, int out_size, void* d_ws, size_t ws_size,
                              hipStream_t stream) {
  const float* Y = (const float*)d_in[0];
  const int* O = (const int*)d_in[1];
  const float* mbar = (const float*)d_in[2];
  const float* wbar = (const float*)d_in[3];
  const float* Sigmaw = (const float*)d_in[4];
  const float* vyp = (const float*)d_in[5];
  float* out = (float*)d_out;
  uint4* bfrag = (uint4*)d_ws;  // 12*3*64*16 = 36864 bytes

  vbpca_prep<<<12, 64, 0, stream>>>(wbar, Sigmaw, bfrag);
  vbpca_main<<<(NN + ROWS - 1) / ROWS, 256, 0, stream>>>(Y, O, bfrag, mbar, vyp, out);
}